// Round 7
// baseline (457.424 us; speedup 1.0000x reference)
//
#include <hip/hip_runtime.h>

#define D_ 160
#define H_ 192
#define W_ 160
#define HW_ (H_*W_)
#define V_ (D_*H_*W_)
#define NTOT (2*V_)

#define TW 32
#define TH 16
#define DC 40
#define NCHUNK (D_/DC)    // 4
#define RH 24             // TH + 8 halo
#define TWP 33            // ws stride pad
#define NBLOCKS (5*12*NCHUNK*2)   // 480

// 16B zero page for OOB load sources (L2-resident after first touch).
__device__ __align__(64) float zpad_g[4] = {0.f, 0.f, 0.f, 0.f};

// RTNE f32x2 -> packed bf16x2 and back (validated: absmax 0.0 through R14).
__device__ inline unsigned pack_bf2(float a, float b) {
  unsigned ua = __float_as_uint(a), ub = __float_as_uint(b);
  ua += 0x7fffu + ((ua >> 16) & 1u);
  ub += 0x7fffu + ((ub >> 16) & 1u);
  return (ua & 0xffff0000u) | (ub >> 16);
}
__device__ inline float2 unpack_bf2(unsigned u) {
  return make_float2(__uint_as_float(u & 0xffff0000u),
                     __uint_as_float(u << 16));
}

// ---------------------------------------------------------------------------
// Fused separable 9x9x9 box filter + NCC.
// R9:  counted vmcnt + raw barriers: 111 -> 87 us.
// R10: FAILED: launch_bounds(256,4) reg-guarantee spilled (97MB scratch).
// R12: FAILED: TH=24 ring state spilled (134MB scratch). Reg budget is tight.
// R13: HURT: bf16 ws pack traded LDS for MORE VALU. Pipes were serialized.
// R14: WIN 86->71us: merged C+B into one region, ONE barrier/step, DC=40.
//      LDS pipe now ~69% busy = the ceiling; VALU 42%.
// R15: delete sIJ. The staged slice has zero reuse (one reader, one pass) --
//      the DMA->LDS->ds_read round trip was pure LDS-pipe tax (~220cyc/step
//      reads + DMA writes). B threads now prefetch their 12-float I/J windows
//      directly into REGISTERS two steps ahead (2 sets, parity-static under
//      an 18-wide unroll = lcm(ring 9, parity 2)). All boundary cases are
//      quad-aligned -> OOB quads load from the zero page; no masking math in
//      the hot path. Compiler scoreboards the loads (no manual vmcnt at all);
//      barrier is lgkm-only. LDS = ws only (31680B).
// Pipeline (u = t%18 static; u9 = t%9; p = t&1):
//   top-bar(t): lgkmcnt(0) + s_barrier            t in [3,51)
//   C(t):       ws[(t+1)&1] (slice t-3) H-sums + D-ring  t in [3,51), emit t>=11
//   B(t):       consume reg set[p] (slice t-2) -> W-sums -> ws[t&1], t in [2,50)
//               then issue loads slice t -> set[p],        t in [0,48)
// ---------------------------------------------------------------------------
__global__ __launch_bounds__(256, 3) void ncc_fused(const float* __restrict__ I,
                                                    const float* __restrict__ J,
                                                    float* __restrict__ bsum) {
  __shared__ float4 ws4[2][RH][TWP];    // 25344 B W-sums f0-3, double-buffered
  __shared__ float  ws1[2][RH][TWP];    //  6336 B W-sums f4,   double-buffered
                                        // total 31680 B

  const int tid = threadIdx.x;
  const int w0 = blockIdx.x * TW;               // 5
  const int h0 = blockIdx.y * TH;               // 12
  const int c0 = (blockIdx.z % NCHUNK) * DC;    // 4 chunks
  const int batch = blockIdx.z / NCHUNK;        // 2

  const float* Ib = I + (size_t)batch * V_;
  const float* Jb = J + (size_t)batch * V_;
  const float* zp = zpad_g;

  // B mapping (tid < 192): wave w -> rows 8w+(tid&7), run (tid>>3)&7.
  // (row varies with LOW lane bits -> ws4-write bank starts spread.)
  const int br = ((tid >> 6) << 3) | (tid & 7);
  const int brun = (tid >> 3) & 7;
  const int bc = brun * 4;

  // B global window: row hr = h0-4+br, cols cb..cb+11 (cb quad-aligned).
  // OOB is exactly quad-granular (W_, w0, cb all multiples of 4).
  const int hr = h0 - 4 + br;
  const int cb = w0 - 4 + 4 * brun;
  const bool rowok = ((unsigned)hr < (unsigned)H_) && (tid < 192);
  const bool q0ok = rowok && ((unsigned)(cb)     < (unsigned)W_);
  const bool q1ok = rowok && ((unsigned)(cb + 4) < (unsigned)W_);
  const bool q2ok = rowok && ((unsigned)(cb + 8) < (unsigned)W_);
  // Per-thread static base addresses (only meaningful when the ok flag holds).
  const float* bI0 = Ib + (size_t)(q0ok ? hr : 0) * W_ + (q0ok ? cb     : 0);
  const float* bI1 = Ib + (size_t)(q1ok ? hr : 0) * W_ + (q1ok ? cb + 4 : 0);
  const float* bI2 = Ib + (size_t)(q2ok ? hr : 0) * W_ + (q2ok ? cb + 8 : 0);
  const float* bJ0 = Jb + (size_t)(q0ok ? hr : 0) * W_ + (q0ok ? cb     : 0);
  const float* bJ1 = Jb + (size_t)(q1ok ? hr : 0) * W_ + (q1ok ? cb + 4 : 0);
  const float* bJ2 = Jb + (size_t)(q2ok ? hr : 0) * W_ + (q2ok ? cb + 8 : 0);

  // C mapping: col tx, output rows hb, hb+1
  const int tx = tid & 31;
  const int hb = (tid >> 5) * 2;

  unsigned ring[5][9];
  float sum0[5], sum1[5];
#pragma unroll
  for (int f = 0; f < 5; ++f) {
    sum0[f] = 0.f; sum1[f] = 0.f;
#pragma unroll
    for (int k = 0; k < 9; ++k) ring[f][k] = 0u;
  }

  // Two prefetch register sets (parity-selected; static index under unroll 18).
  float4 rI0[2], rI1[2], rI2[2], rJ0[2], rJ1[2], rJ2[2];

  float local = 0.f;

#pragma unroll 1
  for (int tb = 0; tb < 54; tb += 18) {
#pragma unroll
    for (int u = 0; u < 18; ++u) {
      const int t = tb + u;              // 0..53
      const int u9 = (u < 9) ? u : u - 9;   // t % 9  (ring slot, static)
      const int p  = u & 1;                 // t % 2  (reg set,  static)

      // ---- top-of-step barrier: B(t-1)'s ws writes visible to C(t);
      //      C(t) reads ws[(t+1)&1], B(t) writes ws[t&1] -> no intra hazard.
      if (t >= 3 && t < DC + 11) {
        asm volatile("s_waitcnt lgkmcnt(0)" ::: "memory");
        __builtin_amdgcn_s_barrier();
      }

      // ---- C: H-dir 9-sums of ws[(t+1)&1] (= slice t-3) + bf16 D-ring ----
      if (t >= 3 && t < DC + 11) {
        const float4 (*W4r)[TWP] = ws4[(t + 1) & 1];
        const float  (*W1r)[TWP] = ws1[(t + 1) & 1];
        float v0 = 0.f, v1 = 0.f, v2 = 0.f, v3 = 0.f, v4 = 0.f;
        float4 k4; float k1v;
#pragma unroll
        for (int k = 0; k < 9; ++k) {
          const float4 a4 = W4r[hb + k][tx];
          const float  a1f = W1r[hb + k][tx];
          if (k == 0) { k4 = a4; k1v = a1f; }
          v0 += a4.x; v1 += a4.y; v2 += a4.z; v3 += a4.w; v4 += a1f;
        }
        const float4 t4 = W4r[hb + 9][tx];
        const float  t1 = W1r[hb + 9][tx];
        float hv0[5], hv1[5];
        hv0[0] = v0; hv0[1] = v1; hv0[2] = v2; hv0[3] = v3; hv0[4] = v4;
        hv1[0] = v0 + t4.x - k4.x;
        hv1[1] = v1 + t4.y - k4.y;
        hv1[2] = v2 + t4.z - k4.z;
        hv1[3] = v3 + t4.w - k4.w;
        hv1[4] = v4 + t1   - k1v;

#pragma unroll
        for (int f = 0; f < 5; ++f) {
          const float2 old = unpack_bf2(ring[f][u9]);
          sum0[f] += hv0[f] - old.x;
          sum1[f] += hv1[f] - old.y;
          ring[f][u9] = pack_bf2(hv0[f], hv1[f]);
        }

        if (t >= 11) {
          const float inv = 1.f / 729.f;
          const float cx0 = sum0[4] - sum0[0] * sum0[1] * inv;
          const float iv0 = sum0[2] - sum0[0] * sum0[0] * inv;
          const float jv0 = sum0[3] - sum0[1] * sum0[1] * inv;
          local += cx0 * cx0 * __builtin_amdgcn_rcpf(iv0 * jv0 + 1e-5f);
          const float cx1 = sum1[4] - sum1[0] * sum1[1] * inv;
          const float iv1 = sum1[2] - sum1[0] * sum1[0] * inv;
          const float jv1 = sum1[3] - sum1[1] * sum1[1] * inv;
          local += cx1 * cx1 * __builtin_amdgcn_rcpf(iv1 * jv1 + 1e-5f);
        }
      }

      // ---- B consume: W-dir 9-sums of slice t-2 from reg set[p] -> ws[t&1]
      if (t >= 2 && t < DC + 10 && tid < 192) {
        const float4 A0 = rI0[p], A1 = rI1[p], A2 = rI2[p];
        const float4 B0 = rJ0[p], B1 = rJ1[p], B2 = rJ2[p];
        const float ai[12] = {A0.x,A0.y,A0.z,A0.w, A1.x,A1.y,A1.z,A1.w,
                              A2.x,A2.y,A2.z,A2.w};
        const float aj[12] = {B0.x,B0.y,B0.z,B0.w, B1.x,B1.y,B1.z,B1.w,
                              B2.x,B2.y,B2.z,B2.w};
        float4* W4 = ws4[t & 1][br];
        float*  W1 = ws1[t & 1][br];
        float s0 = 0.f, s1 = 0.f, s2 = 0.f, s3 = 0.f, s4 = 0.f;
#pragma unroll
        for (int k = 0; k < 9; ++k) {
          const float a = ai[k], b = aj[k];
          s0 += a; s1 += b; s2 += a * a; s3 += b * b; s4 += a * b;
        }
        W4[bc] = make_float4(s0, s1, s2, s3);
        W1[bc] = s4;
#pragma unroll
        for (int m = 1; m < 4; ++m) {
          const float ea = ai[8 + m], eb = aj[8 + m];
          const float la = ai[m - 1], lb = aj[m - 1];
          s0 += ea - la;
          s1 += eb - lb;
          s2 += ea * ea - la * la;
          s3 += eb * eb - lb * lb;
          s4 += ea * eb - la * lb;
          W4[bc + m] = make_float4(s0, s1, s2, s3);
          W1[bc + m] = s4;
        }
      }

      // ---- B issue: slice s = c0-4+t -> reg set[p] (consumed at t+2) ----
      if (t < DC + 8 && tid < 192) {
        const int s = c0 - 4 + t;
        const bool sin = (unsigned)s < (unsigned)D_;
        const size_t so = (size_t)(sin ? s : 0) * HW_;
        rI0[p] = *(const float4*)((sin && q0ok) ? (bI0 + so) : zp);
        rI1[p] = *(const float4*)((sin && q1ok) ? (bI1 + so) : zp);
        rI2[p] = *(const float4*)((sin && q2ok) ? (bI2 + so) : zp);
        rJ0[p] = *(const float4*)((sin && q0ok) ? (bJ0 + so) : zp);
        rJ1[p] = *(const float4*)((sin && q1ok) ? (bJ1 + so) : zp);
        rJ2[p] = *(const float4*)((sin && q2ok) ? (bJ2 + so) : zp);
      }
    }
  }

  // ---- block reduction (reuse ws4 space) -> per-block partial ----
  __syncthreads();   // C(50)'s ws reads consumed before the space is reused
  float* red = (float*)&ws4[0][0][0];
  red[tid] = local;
  __syncthreads();
  for (int s2 = 128; s2 > 0; s2 >>= 1) {
    if (tid < s2) red[tid] += red[tid + s2];
    __syncthreads();
  }
  if (tid == 0) {
    const int bid = (blockIdx.z * 12 + blockIdx.y) * 5 + blockIdx.x;
    bsum[bid] = red[0];
  }
}

__global__ __launch_bounds__(256) void finalize_k(const float* __restrict__ bsum,
                                                  float* __restrict__ out) {
  __shared__ double red[256];
  double d = 0.0;
  for (int i = threadIdx.x; i < NBLOCKS; i += 256) d += (double)bsum[i];
  red[threadIdx.x] = d;
  __syncthreads();
  for (int s = 128; s > 0; s >>= 1) {
    if (threadIdx.x < s) red[threadIdx.x] += red[threadIdx.x + s];
    __syncthreads();
  }
  if (threadIdx.x == 0) out[0] = (float)(-red[0] / (double)NTOT);
}

extern "C" void kernel_launch(void* const* d_in, const int* in_sizes, int n_in,
                              void* d_out, int out_size, void* d_ws, size_t ws_size,
                              hipStream_t stream) {
  const float* I = (const float*)d_in[0];   // y_true
  const float* J = (const float*)d_in[1];   // y_pred
  float* out = (float*)d_out;
  float* bsum = (float*)d_ws;               // 480 floats

  dim3 grid(W_ / TW, H_ / TH, NCHUNK * 2);  // 5 x 12 x 8 = 480 blocks
  ncc_fused<<<grid, 256, 0, stream>>>(I, J, bsum);
  finalize_k<<<1, 256, 0, stream>>>(bsum, out);
}

// Round 8
// 164.356 us; speedup vs baseline: 2.7831x; 2.7831x over previous
//
#include <hip/hip_runtime.h>

#define D_ 160
#define H_ 192
#define W_ 160
#define HW_ (H_*W_)
#define V_ (D_*H_*W_)
#define NTOT (2*V_)

#define TW 32
#define TH 16
#define DC 40
#define NCHUNK (D_/DC)    // 4
#define RH 24             // TH + 8 halo
#define TWP 33            // ws stride pad
#define NBLOCKS (5*12*NCHUNK*2)   // 480

// 16B zero page for OOB load sources (L2-resident after first touch).
__device__ __align__(64) float zpad_g[4] = {0.f, 0.f, 0.f, 0.f};

// RTNE f32x2 -> packed bf16x2 and back (validated: absmax 0.0 through R14).
__device__ inline unsigned pack_bf2(float a, float b) {
  unsigned ua = __float_as_uint(a), ub = __float_as_uint(b);
  ua += 0x7fffu + ((ua >> 16) & 1u);
  ub += 0x7fffu + ((ub >> 16) & 1u);
  return (ua & 0xffff0000u) | (ub >> 16);
}
__device__ inline float2 unpack_bf2(unsigned u) {
  return make_float2(__uint_as_float(u & 0xffff0000u),
                     __uint_as_float(u << 16));
}

// ---------------------------------------------------------------------------
// Fused separable 9x9x9 box filter + NCC.
// R9:  counted vmcnt + raw barriers: 111 -> 87 us.
// R10/R12: FAILED (reg spills: forced cap / ring growth). ~170-reg cliff.
// R13: HURT: bf16 ws pack traded LDS for MORE VALU; pipes were serialized.
// R14: WIN 86->71us: merged C+B region, ONE barrier/step, DC=40. LDS-bound.
// R15: FAILED: depth-2 reg prefetch (48 regs) + 12 ptr regs + 18-unroll
//      blew the 170 budget -> 535MB scratch. Mechanism right, budget wrong.
// R16: same mechanism, half the register bill:
//      - depth-1 prefetch (24 regs): issue end of step t, consume in B(t+1)
//        AFTER barrier + C(t+1) -> ~1500cyc of cover + 16 waves TLP.
//      - 9-wide unroll (no parity set, short live ranges).
//      - row-base pointers rbI/rbJ + cb (5 regs vs 12); per-quad addrs
//        derived in-loop (~18 VALU/step, VALU has headroom).
//      LDS = ws only (31680B). Per-step LDS ~926cyc (C 712 + B-writes 214),
//      -19% vs R14's ~1142 (B re-read 216 + DMA writes gone).
// Pipeline (u = t%9 static):
//   top-bar(t): lgkmcnt(0) + s_barrier            t in [3,51)
//   C(t):   ws[(t+1)&1] (slice t-3 out) H-sums + D-ring, t in [3,51), emit>=11
//   B(t):   consume regs (global slice c0-6+t) -> W-sums -> ws[t&1], t in [2,50)
//   issue(t): global slice c0-5+t -> regs (feeds B(t+1)),  t in [1,49)
// Spill canary: WRITE_SIZE must stay ~KB. R15's 535MB = abort signal.
// ---------------------------------------------------------------------------
__global__ __launch_bounds__(256, 3) void ncc_fused(const float* __restrict__ I,
                                                    const float* __restrict__ J,
                                                    float* __restrict__ bsum) {
  __shared__ float4 ws4[2][RH][TWP];    // 25344 B W-sums f0-3, double-buffered
  __shared__ float  ws1[2][RH][TWP];    //  6336 B W-sums f4,   double-buffered
                                        // total 31680 B

  const int tid = threadIdx.x;
  const int w0 = blockIdx.x * TW;               // 5
  const int h0 = blockIdx.y * TH;               // 12
  const int c0 = (blockIdx.z % NCHUNK) * DC;    // 4 chunks
  const int batch = blockIdx.z / NCHUNK;        // 2

  const float* Ib = I + (size_t)batch * V_;
  const float* Jb = J + (size_t)batch * V_;
  const float* zp = zpad_g;

  // B mapping (tid < 192): wave w -> rows 8w+(tid&7), run (tid>>3)&7.
  // (row varies with LOW lane bits -> ws4-write bank starts spread.)
  const int br = ((tid >> 6) << 3) | (tid & 7);
  const int brun = (tid >> 3) & 7;
  const int bc = brun * 4;

  // B global window: row hr = h0-4+br, cols cb..cb+11 (cb quad-aligned).
  // OOB is exactly quad-granular (W_, w0, cb all multiples of 4).
  const int hr = h0 - 4 + br;
  const int cb = w0 - 4 + 4 * brun;
  const bool rowok = ((unsigned)hr < (unsigned)H_) && (tid < 192);
  const bool q0ok = rowok && ((unsigned)(cb)     < (unsigned)W_);
  const bool q1ok = rowok && ((unsigned)(cb + 4) < (unsigned)W_);
  const bool q2ok = rowok && ((unsigned)(cb + 8) < (unsigned)W_);
  const int hr_ok = rowok ? hr : 0;
  const float* rbI = Ib + (size_t)hr_ok * W_;   // row base (2 regs)
  const float* rbJ = Jb + (size_t)hr_ok * W_;   // row base (2 regs)

  // C mapping: col tx, output rows hb, hb+1
  const int tx = tid & 31;
  const int hb = (tid >> 5) * 2;

  unsigned ring[5][9];
  float sum0[5], sum1[5];
#pragma unroll
  for (int f = 0; f < 5; ++f) {
    sum0[f] = 0.f; sum1[f] = 0.f;
#pragma unroll
    for (int k = 0; k < 9; ++k) ring[f][k] = 0u;
  }

  // Single prefetch register set (depth-1): slice consumed by B next step.
  float4 rI0, rI1, rI2, rJ0, rJ1, rJ2;

  float local = 0.f;

#pragma unroll 1
  for (int tb = 0; tb < 54; tb += 9) {
#pragma unroll
    for (int u = 0; u < 9; ++u) {
      const int t = tb + u;              // 0..53; phases self-guard (51..53 idle)

      // ---- top-of-step barrier: B(t-1)'s ws writes visible to C(t);
      //      C(t) reads ws[(t+1)&1], B(t) writes ws[t&1] -> no intra hazard.
      //      No vmcnt here: in-flight prefetch loads span the barrier.
      if (t >= 3 && t < DC + 11) {
        asm volatile("s_waitcnt lgkmcnt(0)" ::: "memory");
        __builtin_amdgcn_s_barrier();
      }

      // ---- C: H-dir 9-sums of ws[(t+1)&1] (= slice t-3) + bf16 D-ring ----
      if (t >= 3 && t < DC + 11) {
        const float4 (*W4r)[TWP] = ws4[(t + 1) & 1];
        const float  (*W1r)[TWP] = ws1[(t + 1) & 1];
        float v0 = 0.f, v1 = 0.f, v2 = 0.f, v3 = 0.f, v4 = 0.f;
        float4 k4; float k1v;
#pragma unroll
        for (int k = 0; k < 9; ++k) {
          const float4 a4 = W4r[hb + k][tx];
          const float  a1f = W1r[hb + k][tx];
          if (k == 0) { k4 = a4; k1v = a1f; }
          v0 += a4.x; v1 += a4.y; v2 += a4.z; v3 += a4.w; v4 += a1f;
        }
        const float4 t4 = W4r[hb + 9][tx];
        const float  t1 = W1r[hb + 9][tx];
        float hv0[5], hv1[5];
        hv0[0] = v0; hv0[1] = v1; hv0[2] = v2; hv0[3] = v3; hv0[4] = v4;
        hv1[0] = v0 + t4.x - k4.x;
        hv1[1] = v1 + t4.y - k4.y;
        hv1[2] = v2 + t4.z - k4.z;
        hv1[3] = v3 + t4.w - k4.w;
        hv1[4] = v4 + t1   - k1v;

#pragma unroll
        for (int f = 0; f < 5; ++f) {
          const float2 old = unpack_bf2(ring[f][u]);
          sum0[f] += hv0[f] - old.x;
          sum1[f] += hv1[f] - old.y;
          ring[f][u] = pack_bf2(hv0[f], hv1[f]);
        }

        if (t >= 11) {
          const float inv = 1.f / 729.f;
          const float cx0 = sum0[4] - sum0[0] * sum0[1] * inv;
          const float iv0 = sum0[2] - sum0[0] * sum0[0] * inv;
          const float jv0 = sum0[3] - sum0[1] * sum0[1] * inv;
          local += cx0 * cx0 * __builtin_amdgcn_rcpf(iv0 * jv0 + 1e-5f);
          const float cx1 = sum1[4] - sum1[0] * sum1[1] * inv;
          const float iv1 = sum1[2] - sum1[0] * sum1[0] * inv;
          const float jv1 = sum1[3] - sum1[1] * sum1[1] * inv;
          local += cx1 * cx1 * __builtin_amdgcn_rcpf(iv1 * jv1 + 1e-5f);
        }
      }

      // ---- B consume: W-dir 9-sums (global slice c0-6+t) -> ws[t&1] ----
      if (t >= 2 && t < DC + 10 && tid < 192) {
        const float4 A0 = rI0, A1 = rI1, A2 = rI2;
        const float4 B0 = rJ0, B1 = rJ1, B2 = rJ2;
        const float ai[12] = {A0.x,A0.y,A0.z,A0.w, A1.x,A1.y,A1.z,A1.w,
                              A2.x,A2.y,A2.z,A2.w};
        const float aj[12] = {B0.x,B0.y,B0.z,B0.w, B1.x,B1.y,B1.z,B1.w,
                              B2.x,B2.y,B2.z,B2.w};
        float4* W4 = ws4[t & 1][br];
        float*  W1 = ws1[t & 1][br];
        float s0 = 0.f, s1 = 0.f, s2 = 0.f, s3 = 0.f, s4 = 0.f;
#pragma unroll
        for (int k = 0; k < 9; ++k) {
          const float a = ai[k], b = aj[k];
          s0 += a; s1 += b; s2 += a * a; s3 += b * b; s4 += a * b;
        }
        W4[bc] = make_float4(s0, s1, s2, s3);
        W1[bc] = s4;
#pragma unroll
        for (int m = 1; m < 4; ++m) {
          const float ea = ai[8 + m], eb = aj[8 + m];
          const float la = ai[m - 1], lb = aj[m - 1];
          s0 += ea - la;
          s1 += eb - lb;
          s2 += ea * ea - la * la;
          s3 += eb * eb - lb * lb;
          s4 += ea * eb - la * lb;
          W4[bc + m] = make_float4(s0, s1, s2, s3);
          W1[bc + m] = s4;
        }
      }

      // ---- issue: global slice s = c0-5+t -> regs (feeds B(t+1)).
      //      WAR on the same regs: in-order per wave, consume above reads
      //      them before these loads rewrite. ----
      if (t >= 1 && t < DC + 9 && tid < 192) {
        const int s = c0 - 5 + t;
        const bool sin = (unsigned)s < (unsigned)D_;
        const size_t so = (size_t)(sin ? s : 0) * HW_;
        const float* pI = rbI + so + cb;
        const float* pJ = rbJ + so + cb;
        rI0 = *(const float4*)((sin && q0ok) ? pI       : zp);
        rI1 = *(const float4*)((sin && q1ok) ? (pI + 4) : zp);
        rI2 = *(const float4*)((sin && q2ok) ? (pI + 8) : zp);
        rJ0 = *(const float4*)((sin && q0ok) ? pJ       : zp);
        rJ1 = *(const float4*)((sin && q1ok) ? (pJ + 4) : zp);
        rJ2 = *(const float4*)((sin && q2ok) ? (pJ + 8) : zp);
      }
    }
  }

  // ---- block reduction (reuse ws4 space) -> per-block partial ----
  __syncthreads();   // C(50)'s ws reads consumed before the space is reused
  float* red = (float*)&ws4[0][0][0];
  red[tid] = local;
  __syncthreads();
  for (int s2 = 128; s2 > 0; s2 >>= 1) {
    if (tid < s2) red[tid] += red[tid + s2];
    __syncthreads();
  }
  if (tid == 0) {
    const int bid = (blockIdx.z * 12 + blockIdx.y) * 5 + blockIdx.x;
    bsum[bid] = red[0];
  }
}

__global__ __launch_bounds__(256) void finalize_k(const float* __restrict__ bsum,
                                                  float* __restrict__ out) {
  __shared__ double red[256];
  double d = 0.0;
  for (int i = threadIdx.x; i < NBLOCKS; i += 256) d += (double)bsum[i];
  red[threadIdx.x] = d;
  __syncthreads();
  for (int s = 128; s > 0; s >>= 1) {
    if (threadIdx.x < s) red[threadIdx.x] += red[threadIdx.x + s];
    __syncthreads();
  }
  if (threadIdx.x == 0) out[0] = (float)(-red[0] / (double)NTOT);
}

extern "C" void kernel_launch(void* const* d_in, const int* in_sizes, int n_in,
                              void* d_out, int out_size, void* d_ws, size_t ws_size,
                              hipStream_t stream) {
  const float* I = (const float*)d_in[0];   // y_true
  const float* J = (const float*)d_in[1];   // y_pred
  float* out = (float*)d_out;
  float* bsum = (float*)d_ws;               // 480 floats

  dim3 grid(W_ / TW, H_ / TH, NCHUNK * 2);  // 5 x 12 x 8 = 480 blocks
  ncc_fused<<<grid, 256, 0, stream>>>(I, J, bsum);
  finalize_k<<<1, 256, 0, stream>>>(bsum, out);
}